// Round 1
// baseline (234.854 us; speedup 1.0000x reference)
//
#include <hip/hip_runtime.h>

// CCN_2D: N=256 vertices, K=16 regular, C0=16, H=32.
// Structure: CH[i,t,a,:] is one-hot => T[i,t,a,b,c] = Fin[j, P[a], P[b], c],
// layer1: T = s[a]s[b] X[j,c]. A = I_16 collapses contract18 to 8 terms.

constexpr int KN = 16;   // degree k
constexpr int HH = 32;   // hidden H
constexpr int NV = 256;  // vertices

// Effective-weight mapping (A=I, S=tr=16, r=1):
//  sum_b[t,a,c]      -> Wsb = 16*W[g0] + W[g5] + 16*sum(W[g6..g14])   at (x=t,y=a)
//  sum_ab[t,c]       -> W[g1], broadcast over y                       at (x=t)
//  sum_t[a,b,c]      -> 16*W[g2]                                      at (x=a,y=b)  [deferred]
//  sum_tb[a,c]       -> W[g3], broadcast over y                       at (x=a)      [deferred]
//  sum_all[c]        -> W[g4] on diagonal x==y                                      [deferred]
//  T[x,y,y,c]        -> W[g15]   (t==x slice)
//  T[y,x,y,c]        -> W[g16]   (t==y slice)
//  d_ttt[c]          -> W[g17] on diagonal x==y                                     [deferred]

template<int C, int MODE>
__global__ __launch_bounds__(256)
void ccn_layer(const float* __restrict__ Fin,   // MODE0: X (N,C); MODE1: F1 (N,16,16,C)
               const int*   __restrict__ nbrs,  // (N,16)
               const float* __restrict__ W,     // (18*C, 32) row-major
               const float* __restrict__ bias,  // (32)
               const float* __restrict__ fcw,   // (32)  (MODE1 only)
               float*       __restrict__ out)   // MODE0: F1 (N,16,16,32); MODE1: partials (N)
{
    __shared__ float sT[KN * KN * C];             // T_t tile (also reused for deferred weights)
    __shared__ float sWsb[C * HH];
    __shared__ float sWab[C * HH];
    __shared__ float sW16[C * HH];
    __shared__ float sW17[C * HH];
    __shared__ float s_sumb[KN * C];              // sum_b T_t [a][c]
    __shared__ float s_sumtb[KN * C];             // running sum over t of s_sumb
    __shared__ float s_sumab[C];
    __shared__ float s_sumall[C];
    __shared__ float s_dttt[C];
    __shared__ float s_row[KN * HH];              // per-t outputs at (x=t, y, h)
    __shared__ float s_col[KN * HH];              // per-t outputs at (x, y=t, h)
    __shared__ int   s_nbi[KN];
    __shared__ int   s_nbj[KN];
    __shared__ int   s_P[KN];
    __shared__ float s_red[4];

    const int tid = threadIdx.x;
    const int i   = blockIdx.x;
    const int a   = tid >> 4;    // output x
    const int b   = tid & 15;    // output y

    // --- init: effective weights, accumulators ---
    for (int u = tid; u < C * HH; u += 256) {
        float w0 = W[0 * C * HH + u];
        float w5 = W[5 * C * HH + u];
        float acc = 0.f;
        #pragma unroll
        for (int g = 6; g < 15; ++g) acc += W[g * C * HH + u];
        sWsb[u] = 16.f * w0 + w5 + 16.f * acc;
        sWab[u] = W[1 * C * HH + u];
        sW16[u] = W[15 * C * HH + u];
        sW17[u] = W[16 * C * HH + u];
    }
    for (int u = tid; u < KN * C; u += 256) s_sumtb[u] = 0.f;
    if (tid < C) { s_sumall[tid] = 0.f; s_dttt[tid] = 0.f; }
    if (tid < KN) s_nbi[tid] = nbrs[i * KN + tid];

    float pre[HH];
    #pragma unroll
    for (int h = 0; h < HH; ++h) pre[h] = 0.f;
    float sumT[C];
    #pragma unroll
    for (int c = 0; c < C; ++c) sumT[c] = 0.f;

    __syncthreads();

    for (int t = 0; t < KN; ++t) {
        const int j = s_nbi[t];
        if (tid < KN) s_nbj[tid] = nbrs[j * KN + tid];
        __syncthreads();
        if (tid < KN) {
            const int tgt = s_nbi[tid];
            int p = -1;
            #pragma unroll
            for (int q = 0; q < KN; ++q) if (s_nbj[q] == tgt) p = q;
            s_P[tid] = p;
        }
        __syncthreads();
        // --- build T_t[a][b][c] ---
        {
            const int pa = s_P[a], pb = s_P[b];
            float4* dst = (float4*)&sT[(a * KN + b) * C];
            if (pa >= 0 && pb >= 0) {
                const float4* src = (MODE == 0)
                    ? (const float4*)(Fin + j * C)
                    : (const float4*)(Fin + ((j * KN + pa) * KN + pb) * C);
                #pragma unroll
                for (int c4 = 0; c4 < C / 4; ++c4) dst[c4] = src[c4];
            } else {
                const float4 z = make_float4(0.f, 0.f, 0.f, 0.f);
                #pragma unroll
                for (int c4 = 0; c4 < C / 4; ++c4) dst[c4] = z;
            }
        }
        __syncthreads();
        // --- phase A: sum over b ---
        for (int u = tid; u < KN * C; u += 256) {
            const int aa = u / C, cc = u - aa * C;
            float s = 0.f;
            #pragma unroll
            for (int bb = 0; bb < KN; ++bb) s += sT[(aa * KN + bb) * C + cc];
            s_sumb[u] = s;
        }
        __syncthreads();
        // --- phase B: per-channel accumulators ---
        if (tid < C) {
            float sab = 0.f;
            #pragma unroll
            for (int aa = 0; aa < KN; ++aa) sab += s_sumb[aa * C + tid];
            s_sumab[tid] = sab;
            s_sumall[tid] += sab;
            s_dttt[tid] += sT[(t * KN + t) * C + tid];
        }
        for (int u = tid; u < KN * C; u += 256) s_sumtb[u] += s_sumb[u];
        __syncthreads();
        // --- phase C: cooperative row/col matmuls + sumT accumulation ---
        for (int u = tid; u < KN * HH; u += 256) {
            const int y = u >> 5, h = u & 31;
            float accr = 0.f, accc = 0.f;
            for (int c = 0; c < C; ++c) {
                accr += s_sumb[y * C + c] * sWsb[c * HH + h]
                      + s_sumab[c]        * sWab[c * HH + h]
                      + sT[(y * KN + y) * C + c] * sW16[c * HH + h];
                accc += sT[(y * KN + t) * C + c] * sW17[c * HH + h];
            }
            s_row[u] = accr;
            s_col[u] = accc;
        }
        {
            const float* Trow = &sT[(a * KN + b) * C];
            #pragma unroll
            for (int c = 0; c < C; ++c) sumT[c] += Trow[c];
        }
        __syncthreads();
        // --- phase D: scatter into owning threads' registers ---
        if (a == t) {
            #pragma unroll
            for (int h = 0; h < HH; ++h) pre[h] += s_row[b * HH + h];
        }
        if (b == t) {
            #pragma unroll
            for (int h = 0; h < HH; ++h) pre[h] += s_col[a * HH + h];
        }
        // no trailing barrier needed: next iteration has barriers before any
        // conflicting LDS rewrite (s_nbj untouched by phase D; sT/s_row/s_col
        // rewritten only after intervening __syncthreads()).
    }

    __syncthreads();   // all reads of sT done; reuse it for deferred weights
    float* sWt  = sT;                // 16 * W[g2]
    float* sWtb = sT + 1 * C * HH;   // W[g3]
    float* sWal = sT + 2 * C * HH;   // W[g4]
    float* sW18 = sT + 3 * C * HH;   // W[g17]
    for (int u = tid; u < C * HH; u += 256) {
        sWt[u]  = 16.f * W[2 * C * HH + u];
        sWtb[u] = W[3 * C * HH + u];
        sWal[u] = W[4 * C * HH + u];
        sW18[u] = W[17 * C * HH + u];
    }
    __syncthreads();

    // deferred: sum_t and sum_tb terms
    for (int c = 0; c < C; ++c) {
        const float st  = sumT[c];
        const float stb = s_sumtb[a * C + c];
        #pragma unroll
        for (int h = 0; h < HH; ++h)
            pre[h] += st * sWt[c * HH + h] + stb * sWtb[c * HH + h];
    }
    // deferred: diagonal terms
    if (a == b) {
        for (int c = 0; c < C; ++c) {
            const float sal = s_sumall[c];
            const float dt  = s_dttt[c];
            #pragma unroll
            for (int h = 0; h < HH; ++h)
                pre[h] += sal * sWal[c * HH + h] + dt * sW18[c * HH + h];
        }
    }
    // bias + relu
    #pragma unroll
    for (int h = 0; h < HH; ++h) {
        const float v = pre[h] + bias[h];
        pre[h] = v > 0.f ? v : 0.f;
    }

    if (MODE == 0) {
        float4* dst = (float4*)(out + ((i * KN + a) * KN + b) * HH);
        #pragma unroll
        for (int h4 = 0; h4 < HH / 4; ++h4)
            dst[h4] = make_float4(pre[4 * h4], pre[4 * h4 + 1],
                                  pre[4 * h4 + 2], pre[4 * h4 + 3]);
    } else {
        float local = 0.f;
        #pragma unroll
        for (int h = 0; h < HH; ++h) local += pre[h] * fcw[h];
        #pragma unroll
        for (int off = 32; off > 0; off >>= 1)
            local += __shfl_down(local, off, 64);
        if ((tid & 63) == 0) s_red[tid >> 6] = local;
        __syncthreads();
        if (tid == 0) out[i] = s_red[0] + s_red[1] + s_red[2] + s_red[3];
    }
}

__global__ __launch_bounds__(256)
void ccn_finalize(const float* __restrict__ partials,
                  const float* __restrict__ fc_b,
                  float* __restrict__ out)
{
    float v = partials[threadIdx.x];
    #pragma unroll
    for (int off = 32; off > 0; off >>= 1)
        v += __shfl_down(v, off, 64);
    __shared__ float s_red[4];
    if ((threadIdx.x & 63) == 0) s_red[threadIdx.x >> 6] = v;
    __syncthreads();
    if (threadIdx.x == 0)
        out[0] = s_red[0] + s_red[1] + s_red[2] + s_red[3] + fc_b[0];
}

extern "C" void kernel_launch(void* const* d_in, const int* in_sizes, int n_in,
                              void* d_out, int out_size, void* d_ws, size_t ws_size,
                              hipStream_t stream) {
    const float* X    = (const float*)d_in[0];   // (256,16)
    const int*   nbrs = (const int*)  d_in[1];   // (256,16)
    const float* W1   = (const float*)d_in[2];   // (288,32)
    const float* b1   = (const float*)d_in[3];   // (32)
    const float* W2   = (const float*)d_in[4];   // (576,32)
    const float* b2   = (const float*)d_in[5];   // (32)
    const float* fc_w = (const float*)d_in[6];   // (32,1)
    const float* fc_b = (const float*)d_in[7];   // (1)
    float* outp = (float*)d_out;

    float* F1       = (float*)d_ws;               // 256*16*16*32 floats = 8 MB
    float* partials = F1 + NV * KN * KN * HH;     // 256 floats

    ccn_layer<16, 0><<<NV, 256, 0, stream>>>(X,  nbrs, W1, b1, nullptr, F1);
    ccn_layer<32, 1><<<NV, 256, 0, stream>>>(F1, nbrs, W2, b2, fc_w, partials);
    ccn_finalize<<<1, 256, 0, stream>>>(partials, fc_b, outp);
}